// Round 6
// baseline (55.200 us; speedup 1.0000x reference)
//
#include <hip/hip_runtime.h>

#define DISP_RANGE 10
#define OUT_D 21
#define A_ 9
#define D_ 128
#define HW_ 4096   // 64*64

// Role 0 (uh): out[b,0,a,k,h,w] = wt_k * sum_{dd in win_k} uh[b,a,dd-32+h,h,w]  (0 if row OOB)
// Role 1 (vw): out[b,1,a,k,h,w] = wt_k * sum_{dd in win_k} vw[b,a,dd-32+w,h,w]  (0 if row OOB)
//
// Block = (b, a, h-group of 4). All global traffic in 1 KB contiguous
// wave-requests: input rows staged as (row, h0..h0+3, all w) spans via
// global_load_lds(16B/lane), in 32-row chunks double-buffered (2x32KB LDS);
// output stored as (k, h0..h0+3, all w) 1 KB spans from an LDS tile.
// Thread = (hh, w): hh = wave id (0..3) -> h = h0+hh; per-thread acc[21].
// vw LDS read addr == 257*w + const -> bank-conflict-free (2-way only).

template<int AD, int ROLE> struct P {
    static constexpr int L   = 2 * DISP_RANGE * AD + 1;     // 21/41/61/81
    static constexpr int S0  = 64 - DISP_RANGE * AD;        // 54/44/34/24
    // unclamped staged-row count relative to rbase:
    //   role 0: rows [S0-32+h0, S0+L-32+h0+3)  -> L+3
    //   role 1: rows [S0-32,    S0+L-32+63+1)  -> L+63
    static constexpr int NR  = (ROLE == 0) ? (L + 3) : (L + 63);
    static constexpr int NCH = (NR + 31) / 32;              // 32-row chunks
};

template<int AD, int ROLE>
__device__ __forceinline__ void stage_chunk(
    const float* __restrict__ in, size_t plane, int h0, int rbase,
    float* lds, int ch, int wid, int lane)
{
    using p = P<AD, ROLE>;
    float* dst = lds + (ch & 1) * 8192;
#pragma unroll
    for (int j = 0; j < 8; ++j) {
        const int rr = wid + 4 * j;                 // 0..31 (wave-uniform)
        const int grow = rbase + ch * 32 + rr;      // global row
        if ((ch * 32 + rr) < p::NR && grow >= 0 && grow < D_) {
            const float* s = in + plane + (size_t)grow * HW_
                           + (size_t)(h0 * 64) + (size_t)(lane * 4);
            __builtin_amdgcn_global_load_lds(
                (const __attribute__((address_space(1))) void*)s,
                (__attribute__((address_space(3))) void*)(dst + rr * 256 + lane * 4),
                16, 0, 0);
        }
    }
}

template<int AD, int ROLE>
__device__ __forceinline__ void run(
    const float* __restrict__ in, float* __restrict__ out,
    float* lds, int b, int a, int h0, int t)
{
    using p = P<AD, ROLE>;
    const int lane = t & 63;
    const int w    = lane;
    const int wid  = t >> 6;                        // hh: h = h0 + wid

    const size_t plane = (size_t)(b * A_ + a) * D_ * HW_;
    const int rbase = (p::S0 - 32) + (ROLE == 0 ? h0 : 0);

    float acc[OUT_D];
#pragma unroll
    for (int k = 0; k < OUT_D; ++k) acc[k] = 0.0f;

    stage_chunk<AD, ROLE>(in, plane, h0, rbase, lds, 0, wid, lane);
    __syncthreads();

#pragma unroll
    for (int ch = 0; ch < p::NCH; ++ch) {
        if (ch + 1 < p::NCH)
            stage_chunk<AD, ROLE>(in, plane, h0, rbase, lds, ch + 1, wid, lane);

        const float* buf = lds + (ch & 1) * 8192;
#pragma unroll
        for (int k = 0; k < OUT_D; ++k) {
            const int s = (k * p::L) / OUT_D;
            const int e = ((k + 1) * p::L + OUT_D - 1) / OUT_D;
#pragma unroll
            for (int dd = p::S0 + s; dd < p::S0 + e; ++dd) {
                const int rrel0 = dd - p::S0;       // compile-time after unroll
                if (ROLE == 0) {
                    // r spans [rrel0, rrel0+4) over hh -> chunk-skip constexpr
                    if (rrel0 + 3 >= ch * 32 && rrel0 < ch * 32 + 32) {
                        const int  r   = rrel0 + wid - ch * 32;
                        const int  row = rbase + ch * 32 + r;   // = dd-32+h0+hh
                        const bool ok  = (r >= 0) && (r < 32) && (row >= 0) && (row < D_);
                        const int  rc  = r < 0 ? 0 : (r > 31 ? 31 : r);
                        const float v = buf[rc * 256 + wid * 64 + w];
                        acc[k] += ok ? v : 0.0f;
                    }
                } else {
                    // r spans [rrel0, rrel0+64) over w -> chunk-skip constexpr
                    if (rrel0 + 63 >= ch * 32 && rrel0 < ch * 32 + 32) {
                        const int r  = rrel0 + w - ch * 32;
                        bool ok = (r >= 0) && (r < 32);
                        if (AD == 4) {
                            const int row = dd - 32 + w;        // global validity
                            ok = ok && (row >= 0) && (row < D_);
                        }
                        const int rc = r < 0 ? 0 : (r > 31 ? 31 : r);
                        const float v = buf[rc * 256 + wid * 64 + w];
                        acc[k] += ok ? v : 0.0f;
                    }
                }
            }
        }
        __syncthreads();   // buf[ch] readers done; buf[ch+1] DMA drained
    }

    // ---- epilogue: acc -> LDS tile -> 1 KB stores ----
#pragma unroll
    for (int k = 0; k < OUT_D; ++k) {
        const int s = (k * p::L) / OUT_D;
        const int e = ((k + 1) * p::L + OUT_D - 1) / OUT_D;
        lds[k * 256 + wid * 64 + w] = acc[k] * (1.0f / (float)(e - s));
    }
    __syncthreads();

    const size_t ob = ((size_t)((b * 2 + ROLE) * A_ + a) * OUT_D) * HW_
                    + (size_t)(h0 * 64);
#pragma unroll
    for (int it = 0; it < 6; ++it) {
        const int k = wid + 4 * it;
        if (k < OUT_D) {
            const float4 v = reinterpret_cast<const float4*>(lds)[k * 64 + lane];
            *reinterpret_cast<float4*>(out + ob + (size_t)k * HW_ + (size_t)(lane * 4)) = v;
        }
    }
}

template<int AD>
__device__ __forceinline__ void run_role(
    const float* __restrict__ uh, const float* __restrict__ vw,
    float* __restrict__ out, float* lds,
    int b, int a, int h0, int t, int role)
{
    if (role == 0) run<AD, 0>(uh, out, lds, b, a, h0, t);
    else           run<AD, 1>(vw, out, lds, b, a, h0, t);
}

__global__ __launch_bounds__(256, 2) void cost_volume_kernel(
    const float* __restrict__ uh,
    const float* __restrict__ vw,
    float* __restrict__ out)
{
    __shared__ float lds[16384];   // 2 x 32 KiB chunk buffers

    const int h0   = (int)blockIdx.x * 4;
    const int y    = (int)blockIdx.y;          // 0..17
    const int b    = (int)blockIdx.z;
    const int a    = (y >= A_) ? (y - A_) : y;
    const int role = (y >= A_) ? 1 : 0;
    const int t    = (int)threadIdx.x;

    switch (a) {
        case 3: case 4: case 5:
            run_role<1>(uh, vw, out, lds, b, a, h0, t, role); break;
        case 2: case 6:
            run_role<2>(uh, vw, out, lds, b, a, h0, t, role); break;
        case 1: case 7:
            run_role<3>(uh, vw, out, lds, b, a, h0, t, role); break;
        default:   // 0, 8
            run_role<4>(uh, vw, out, lds, b, a, h0, t, role); break;
    }
}

extern "C" void kernel_launch(void* const* d_in, const int* in_sizes, int n_in,
                              void* d_out, int out_size, void* d_ws, size_t ws_size,
                              hipStream_t stream) {
    const float* uh = (const float*)d_in[0];   // [8,9,128,64,64] f32
    const float* vw = (const float*)d_in[1];   // [8,9,128,64,64] f32
    float* out = (float*)d_out;                // [8,2,9,21,64,64] f32

    dim3 grid(16, 2 * A_, 8);   // (h-group, role*a, b) = 2304 blocks
    dim3 block(256);
    cost_volume_kernel<<<grid, block, 0, stream>>>(uh, vw, out);
}

// Round 7
// 41.086 us; speedup vs baseline: 1.3435x; 1.3435x over previous
//
#include <hip/hip_runtime.h>

#define DISP_RANGE 10
#define OUT_D 21
#define B_ 8
#define A_ 9
#define D_ 128
#define HW_ 4096   // 64*64

// cost[b,0,a,k,h,w] = wt_k * sum_{dd in [START0+s_k, START0+e_k)} uh[b,a, dd-32+h, h, w]  (0 if row OOB)
// cost[b,1,a,k,h,w] = wt_k * sum_{dd in [START0+s_k, START0+e_k)} vw[b,a, dd-32+w, h, w]  (0 if row OOB)
// R3 champion structure (single launch, constexpr AD paths, async global_load_lds
// staging, stride-65 conflict-free diagonal LDS read) + NON-TEMPORAL output
// stores: output (49.5 MB/replay) is write-once, never re-read -> NT no-allocate
// keeps it out of L3 so the ~253 MB input set stays Infinity-Cache-resident
// across replays (302 MB footprint vs 256 MB L3 was thrashing ~89 MB/replay).

template<int AD, int WID>
__device__ __forceinline__ void compute_group(
    const float* __restrict__ uh_slice,   // uh + plane + h*64
    const float* lds,                     // staged vw rows [LO,HI)
    float* __restrict__ out0,             // out + base(n=0) + w
    float* __restrict__ out1,             // out + base(n=1) + w
    int h, int w)
{
    constexpr int L      = 2 * DISP_RANGE * AD + 1;
    constexpr int START0 = (D_ / 2) - DISP_RANGE * AD;
    constexpr int LO     = (START0 - 32 < 0) ? 0 : (START0 - 32);
    constexpr int HI     = (START0 + L + 31 > D_) ? D_ : (START0 + L + 31);
    constexpr int K0     = (WID == 0) ? 0 : (6 + 5 * (WID - 1));   // 0,6,11,16
    constexpr int K1     = K0 + ((WID == 0) ? 6 : 5);
    constexpr int NK     = K1 - K0;
    constexpr int S0     = (K0 * L) / OUT_D;
    constexpr int E1     = (K1 * L + OUT_D - 1) / OUT_D;           // e_{K1-1}

    float acc0[NK];
    float acc1[NK];
#pragma unroll
    for (int i = 0; i < NK; ++i) { acc0[i] = 0.0f; acc1[i] = 0.0f; }

#pragma unroll
    for (int dd = START0 + S0; dd < START0 + E1; ++dd) {
        // uh path: clamp row, unconditional (in-bounds) load, select
        const int  row  = dd - 32 + h;
        const bool ok0  = (row >= 0) && (row < D_);
        const int  rowc = row < 0 ? 0 : (row > D_ - 1 ? D_ - 1 : row);
        float v0 = uh_slice[(size_t)rowc * HW_ + (size_t)w];
        v0 = ok0 ? v0 : 0.0f;

        // vw path from LDS: per-lane diagonal row, clamp + select
        const int  rv   = dd - 32 + w;
        const bool ok1  = (rv >= LO) && (rv < HI);
        const int  rvc  = rv < LO ? LO : (rv > HI - 1 ? HI - 1 : rv);
        float v1 = lds[(rvc - LO) * 64 + w];
        v1 = ok1 ? v1 : 0.0f;

        // compile-time window membership -> pure adds
#pragma unroll
        for (int k = K0; k < K1; ++k) {
            if (dd >= START0 + (k * L) / OUT_D &&
                dd <  START0 + ((k + 1) * L + OUT_D - 1) / OUT_D) {
                acc0[k - K0] += v0;
                acc1[k - K0] += v1;
            }
        }
    }

#pragma unroll
    for (int k = K0; k < K1; ++k) {
        const int   s  = (k * L) / OUT_D;
        const int   e  = ((k + 1) * L + OUT_D - 1) / OUT_D;
        const float wt = 1.0f / (float)(e - s);
        __builtin_nontemporal_store(acc0[k - K0] * wt, &out0[(size_t)k * HW_]);
        __builtin_nontemporal_store(acc1[k - K0] * wt, &out1[(size_t)k * HW_]);
    }
}

template<int AD>
__device__ __forceinline__ void run_block(
    const float* __restrict__ uh,
    const float* __restrict__ vw,
    float* __restrict__ out,
    float* lds,
    int b, int a, int h, int t)
{
    constexpr int L      = 2 * DISP_RANGE * AD + 1;
    constexpr int START0 = (D_ / 2) - DISP_RANGE * AD;
    constexpr int LO     = (START0 - 32 < 0) ? 0 : (START0 - 32);
    constexpr int HI     = (START0 + L + 31 > D_) ? D_ : (START0 + L + 31);
    constexpr int NROWS  = HI - LO;        // 84 / 104 / 124 / 128 (all %4==0)
    constexpr int NCH    = NROWS / 4;      // 4-row, 1KB chunks

    const int lane = t & 63;
    const int w    = lane;
    const int wid  = t >> 6;

    const size_t plane = (size_t)(b * A_ + a) * D_ * HW_;
    const float* uh_slice = uh + plane + (size_t)h * 64;
    const float* vw_slice = vw + plane + (size_t)h * 64;

    // ---- async stage vw rows [LO,HI) into LDS ----
    // chunk c = rows [LO+4c, LO+4c+4); wave (c&3) issues it; lane l covers
    // row +(l>>4), float4 col (l&15). LDS dest = base c*1024B + l*16B (linear).
#pragma unroll
    for (int c = 0; c < NCH; ++c) {
        if ((c & 3) == wid) {
            const float* src = vw_slice
                + (size_t)(LO + c * 4 + (lane >> 4)) * HW_
                + (size_t)((lane & 15) * 4);
            __builtin_amdgcn_global_load_lds(
                (const __attribute__((address_space(1))) void*)src,
                (__attribute__((address_space(3))) void*)&lds[c * 256],
                16, 0, 0);
        }
    }
    __syncthreads();

    const size_t out_b0 = ((size_t)(b * 2) * A_ + a) * OUT_D * HW_
                        + (size_t)h * 64 + (size_t)w;
    const size_t out_b1 = out_b0 + (size_t)A_ * OUT_D * HW_;
    float* out0 = out + out_b0;
    float* out1 = out + out_b1;

    switch (wid) {
        case 0: compute_group<AD, 0>(uh_slice, lds, out0, out1, h, w); break;
        case 1: compute_group<AD, 1>(uh_slice, lds, out0, out1, h, w); break;
        case 2: compute_group<AD, 2>(uh_slice, lds, out0, out1, h, w); break;
        default: compute_group<AD, 3>(uh_slice, lds, out0, out1, h, w); break;
    }
}

__global__ __launch_bounds__(256) void cost_volume_kernel(
    const float* __restrict__ uh,
    const float* __restrict__ vw,
    float* __restrict__ out)
{
    __shared__ float lds[D_ * 64];   // 32 KiB (max case AD=4)

    const int h = blockIdx.x;
    const int a = blockIdx.y;
    const int b = blockIdx.z;
    const int t = (int)threadIdx.x;

    // AD = max(|a-4|,1), block-uniform branch into constexpr path
    switch (a) {
        case 3: case 4: case 5:
            run_block<1>(uh, vw, out, lds, b, a, h, t); break;
        case 2: case 6:
            run_block<2>(uh, vw, out, lds, b, a, h, t); break;
        case 1: case 7:
            run_block<3>(uh, vw, out, lds, b, a, h, t); break;
        default:   // 0, 8
            run_block<4>(uh, vw, out, lds, b, a, h, t); break;
    }
}

extern "C" void kernel_launch(void* const* d_in, const int* in_sizes, int n_in,
                              void* d_out, int out_size, void* d_ws, size_t ws_size,
                              hipStream_t stream) {
    const float* uh = (const float*)d_in[0];   // [8,9,128,64,64] f32
    const float* vw = (const float*)d_in[1];   // [8,9,128,64,64] f32
    float* out = (float*)d_out;                // [8,2,9,21,64,64] f32

    dim3 grid(64, A_, B_);   // (h, a, b) = 4608 blocks
    dim3 block(256);
    cost_volume_kernel<<<grid, block, 0, stream>>>(uh, vw, out);
}